// Round 4
// baseline (221.084 us; speedup 1.0000x reference)
//
#include <hip/hip_runtime.h>
#include <hip/hip_bf16.h>
#include <stdint.h>

#define B_SZ 4096
#define D_K  2048   // D_IN + D_H
#define DH   1024

#define BM 128      // M rows per block
#define BN_H 32     // h columns per block (x4 gates = 128 N columns)
#define BK 32       // K elements per LDS tile (1 MFMA k-step), double-buffered

typedef __attribute__((ext_vector_type(8))) short short8;
typedef __attribute__((ext_vector_type(4))) float floatx4;

__device__ __forceinline__ float fast_sigmoid(float x) {
  return 1.0f / (1.0f + __expf(-x));
}
__device__ __forceinline__ float fast_tanh(float x) {
  return 2.0f / (1.0f + __expf(-2.0f * x)) - 1.0f;
}

// Pack two fp32 -> bf16x2 (RNE) entirely in registers.
__device__ __forceinline__ uint32_t bf16pk(float a, float b) {
  union { float f; uint32_t u; } ua, ub;
  ua.f = a; ub.f = b;
  uint32_t x = ua.u + (0x7FFFu + ((ua.u >> 16) & 1u));
  uint32_t y = ub.u + (0x7FFFu + ((ub.u >> 16) & 1u));
  return (x >> 16) | (y & 0xFFFF0000u);
}

// Fully-coalesced cast: each thread reads ONE float4 (lane i -> base+i*16B)
// and writes ONE uint2 (8B). No strided access anywhere.
//  Abf[m][k] = (k<1024 ? x[m][k] : h_prev[m][k-1024])          [4096][2048]
//  Wbf[g*1024+h][k] = W_g[h][k]   (gate-major concat)          [4096][2048]
__global__ __launch_bounds__(256) void prep_kernel(
    const float* __restrict__ xin, const float* __restrict__ hprev,
    const float* __restrict__ Wi, const float* __restrict__ Wf,
    const float* __restrict__ Wc, const float* __restrict__ Wo,
    uint32_t* __restrict__ Abf, uint32_t* __restrict__ Wbf)
{
  const int NT = (B_SZ * D_K) / 4;  // threads per matrix (4 elems/thread)
  int t = blockIdx.x * blockDim.x + threadIdx.x;
  const float* src;
  uint32_t* dst;
  if (t < NT) {
    int idx4 = t * 4;
    int m = idx4 >> 11;
    int k = idx4 & (D_K - 1);
    src = (k < 1024) ? (xin + (size_t)m * 1024 + k)
                     : (hprev + (size_t)m * 1024 + (k - 1024));
    dst = Abf + (size_t)t * 2;
  } else {
    int u = t - NT;
    int idx4 = u * 4;
    int n = idx4 >> 11;
    int k = idx4 & (D_K - 1);
    int g = n >> 10, h = n & 1023;
    const float* wsrc = (g == 0) ? Wi : (g == 1) ? Wf : (g == 2) ? Wc : Wo;
    src = wsrc + (size_t)h * D_K + k;
    dst = Wbf + (size_t)u * 2;
  }
  float4 f = *(const float4*)src;
  uint2 v;
  v.x = bf16pk(f.x, f.y);
  v.y = bf16pk(f.z, f.w);
  *(uint2*)dst = v;
}

// Fused GEMM + LSTM gate epilogue, double-buffered LDS.
// Block tile: 128 M x (4 gates x 32 h). 4 waves: 2(M64) x 2(h16).
// Wave tile 64x64 = 4 M-frags x 4 gate-frags; gates colocate per-lane.
// BK=32 dbuf: ONE barrier per K-iter; loads for tile kt+1 issue BEFORE
// compute of tile kt -> the vmcnt(0) drain at the barrier is covered by
// ~16 MFMAs of compute. LDS = 2 x (8+8) KB = 32 KB -> 3 blocks/CU intact.
// Bank swizzle (64B rows, 4 x 16B chunks): logical chunk c of row r lives at
// physical chunk c ^ ((r>>1)&3); per 16-lane quarter every 4-bank group is
// hit by exactly 2 lanes (2-way = free). Staging realizes the swizzle by
// permuting the global SOURCE chunk (global_load_lds forces dst=base+lane*16).
// XCD swizzle: XCD k (blockId%8) owns h0-slices {4k..4k+3} -> W working set
// 2 MB per XCD-L2.
__global__ __launch_bounds__(256, 3) void lstm_gemm_kernel(
    const __hip_bfloat16* __restrict__ A,   // [4096][2048]
    const __hip_bfloat16* __restrict__ W,   // [4096][2048] gate-major
    const float* __restrict__ bi, const float* __restrict__ bfv,
    const float* __restrict__ bc, const float* __restrict__ bo,
    const float* __restrict__ cprev,
    float* __restrict__ out)                // [h_next | c_next]
{
  __shared__ __align__(16) __hip_bfloat16 lA[2][BM * BK];   // 2 x 8 KB
  __shared__ __align__(16) __hip_bfloat16 lB[2][128 * BK];  // 2 x 8 KB

  // XCD-aware block swizzle (1D grid, 1024 blocks)
  const int l = blockIdx.x;
  const int q = l >> 3;
  const int mIdx = q & 31;
  const int hIdx = (l & 7) * 4 + (q >> 5);
  const int m0 = mIdx * BM;
  const int h0 = hIdx * BN_H;

  const int tid = threadIdx.x;
  const int wave = tid >> 6;
  const int lane = tid & 63;
  const int wm = wave >> 1;   // M half (64 rows)
  const int wn = wave & 1;    // h half (16 cols)

  // ---- staging geometry: one load = 64 lanes x 16B = 16 rows of 64B.
  const int sr = lane >> 2;               // row within 16-row group
  const int pc = lane & 3;                // physical chunk (forced by HW)
  const int gc = pc ^ ((sr >> 1) & 3);    // swizzled global source chunk

  // 2 A-strips + 2 B-strips per wave; strip j covers rows j*64 + wave*16 + sr
  const __hip_bfloat16* aSrc[2];
  const __hip_bfloat16* bSrc[2];
  int aOff[2], bOff[2];   // LDS element offsets (buffer 0)
  #pragma unroll
  for (int j = 0; j < 2; ++j) {
    int row = j * 64 + wave * 16 + sr;
    aSrc[j] = A + (size_t)(m0 + row) * D_K + gc * 8;
    aOff[j] = row * BK + pc * 8;
    // B tile row r: gate = r>>5, h = h0 + (r&31)
    bSrc[j] = W + (size_t)((row >> 5) * DH + h0 + (row & 31)) * D_K + gc * 8;
    bOff[j] = row * BK + pc * 8;
  }

  floatx4 acc[4][4];
  #pragma unroll
  for (int i = 0; i < 4; ++i)
    #pragma unroll
    for (int j = 0; j < 4; ++j)
      acc[i][j] = (floatx4){0.f, 0.f, 0.f, 0.f};

  // ---- fragment-read geometry
  const int fr = lane & 15;               // row within 16-row frag
  const int kq = lane >> 4;               // k quarter (16B chunk index)
  const int cx = ((kq ^ ((fr >> 1) & 3)) * 8);  // swizzled element offset

  const int NITER = D_K / BK;  // 64

  // preload tile 0 -> buffer 0
  #pragma unroll
  for (int j = 0; j < 2; ++j) {
    __builtin_amdgcn_global_load_lds(
        (const __attribute__((address_space(1))) void*)(aSrc[j]),
        (__attribute__((address_space(3))) void*)&lA[0][aOff[j]], 16, 0, 0);
    __builtin_amdgcn_global_load_lds(
        (const __attribute__((address_space(1))) void*)(bSrc[j]),
        (__attribute__((address_space(3))) void*)&lB[0][bOff[j]], 16, 0, 0);
  }
  __syncthreads();

  int p = 0;
  for (int kt = 0; kt < NITER; ++kt) {
    // issue next tile's loads into the other buffer (overlaps with compute)
    if (kt + 1 < NITER) {
      const int koff = (kt + 1) * BK;
      #pragma unroll
      for (int j = 0; j < 2; ++j) {
        __builtin_amdgcn_global_load_lds(
            (const __attribute__((address_space(1))) void*)(aSrc[j] + koff),
            (__attribute__((address_space(3))) void*)&lA[p ^ 1][aOff[j]], 16, 0, 0);
        __builtin_amdgcn_global_load_lds(
            (const __attribute__((address_space(1))) void*)(bSrc[j] + koff),
            (__attribute__((address_space(3))) void*)&lB[p ^ 1][bOff[j]], 16, 0, 0);
      }
    }

    // compute on current buffer
    short8 bfr[4];
    #pragma unroll
    for (int g = 0; g < 4; ++g)
      bfr[g] = *(const short8*)&lB[p][(g * 32 + wn * 16 + fr) * BK + cx];
    #pragma unroll
    for (int i = 0; i < 4; ++i) {
      short8 af = *(const short8*)&lA[p][(wm * 64 + i * 16 + fr) * BK + cx];
      acc[i][0] = __builtin_amdgcn_mfma_f32_16x16x32_bf16(af, bfr[0], acc[i][0], 0, 0, 0);
      acc[i][1] = __builtin_amdgcn_mfma_f32_16x16x32_bf16(af, bfr[1], acc[i][1], 0, 0, 0);
      acc[i][2] = __builtin_amdgcn_mfma_f32_16x16x32_bf16(af, bfr[2], acc[i][2], 0, 0, 0);
      acc[i][3] = __builtin_amdgcn_mfma_f32_16x16x32_bf16(af, bfr[3], acc[i][3], 0, 0, 0);
    }

    __syncthreads();   // single barrier: drains next-tile loads (covered by MFMAs)
    p ^= 1;
  }

  // Epilogue: C/D layout col=lane&15, row=(lane>>4)*4+reg.
  const int col = lane & 15;
  const int rq = lane >> 4;
  const int h = h0 + wn * 16 + col;
  const float bias_i = bi[h], bias_f = bfv[h], bias_c = bc[h], bias_o = bo[h];
  float* hout = out;
  float* cout = out + (size_t)B_SZ * DH;
  #pragma unroll
  for (int i = 0; i < 4; ++i) {
    int mb = m0 + wm * 64 + i * 16 + rq * 4;
    #pragma unroll
    for (int r = 0; r < 4; ++r) {
      int m = mb + r;
      float zi = acc[i][0][r] + bias_i;
      float zf = acc[i][1][r] + bias_f;
      float zc = acc[i][2][r] + bias_c;
      float zo = acc[i][3][r] + bias_o;
      float ig = fast_sigmoid(zi);
      float fg = fast_sigmoid(zf);
      float cg = fast_tanh(zc);
      float og = fast_sigmoid(zo);
      float cp = cprev[(size_t)m * DH + h];
      float cn = fg * cp + ig * cg;
      float hn = og * fast_tanh(cn);
      hout[(size_t)m * DH + h] = hn;
      cout[(size_t)m * DH + h] = cn;
    }
  }
}

extern "C" void kernel_launch(void* const* d_in, const int* in_sizes, int n_in,
                              void* d_out, int out_size, void* d_ws, size_t ws_size,
                              hipStream_t stream)
{
  const float* xin   = (const float*)d_in[0];
  const float* hprev = (const float*)d_in[1];
  const float* cprev = (const float*)d_in[2];
  const float* Wi    = (const float*)d_in[3];
  const float* bi    = (const float*)d_in[4];
  const float* Wf    = (const float*)d_in[5];
  const float* bfv   = (const float*)d_in[6];
  const float* Wc    = (const float*)d_in[7];
  const float* bc    = (const float*)d_in[8];
  const float* Wo    = (const float*)d_in[9];
  const float* bo    = (const float*)d_in[10];
  float* out = (float*)d_out;

  __hip_bfloat16* Abf = (__hip_bfloat16*)d_ws;                 // 16 MB
  __hip_bfloat16* Wbf = Abf + (size_t)B_SZ * D_K;              // 16 MB

  const int totalThreads = 2 * (B_SZ * D_K / 4);               // 4M threads
  prep_kernel<<<totalThreads / 256, 256, 0, stream>>>(
      xin, hprev, Wi, Wf, Wc, Wo, (uint32_t*)Abf, (uint32_t*)Wbf);

  lstm_gemm_kernel<<<dim3(1024), 256, 0, stream>>>(
      Abf, Wbf, bi, bfv, bc, bo, cprev, out);
}